// Round 10
// baseline (2102.276 us; speedup 1.0000x reference)
//
#include <hip/hip_runtime.h>
#include <hip/hip_bf16.h>

#define NN 10368
#define EE 207360
#define TT 16

// ---- workspace layout (float offsets) ---- (r7-verified layout, 24.65 MB)
#define O_W0AT    0
#define O_W0BT    9216
#define O_WHHT    18432
#define O_WIHXT   55296
#define O_WCOMBT  92160
#define O_GB      129024
#define O_LOSS    129408
#define O_WIN0T   129424
#define O_WINT    134032
#define O_H       161680
#define O_C       (O_H  + NN*96)
#define O_A       (O_C  + NN*96)
#define O_BV      (O_A  + NN*96)
#define O_S2      (O_BV + NN*96)
#define O_X       (O_S2 + NN*96)
#define O_WFRAG   (O_X  + NN*96)   // ushort region: 2 layers x 3 levels x 18 tiles x 512 shorts
// OPTIONAL region — only used if ws_size is big enough (checked at launch):
#define O_GX      (O_WFRAG + 27648) // [384][NN] f32 TRANSPOSED: gb + W_ihx @ x, gx2[col][node]
// Overlay regions on O_X (MFMA path only; nothing writes O_X in that path):
#define O_WL2     O_X               // lstm gate-weight frags: 3 lev x 24 nt x 6 ks x 64 x 8 shorts
#define O_WAB2    (O_X + 110592)    // A/B weight frags: 3 lev x 12 nt x 3 ks x 64 x 8 shorts
#define O_WO      (O_X + 138240)    // outW frags: 3 lev x 3 ks x 64 x 8 shorts (persistent)
// Staging frags in O_S2 (free until first k_edge; consumed only by k_input_mf):
#define SF_WIN0   O_S2              // 3 lev x 6 nt x 2 ks frags (K=48 zero-padded)
#define SF_WIN    (O_S2 + 9216)     // 3 lev x 3 layer x 6 nt x 3 ks frags
#define SF_WX     (O_S2 + 50688)    // 3 lev x 24 nt x 3 ks frags (W_ihx)

using bf16x8 = __attribute__((ext_vector_type(8))) short;
using s16x4  = __attribute__((ext_vector_type(4))) short;
using f32x4  = __attribute__((ext_vector_type(4))) float;

__device__ __forceinline__ float sigm(float x){ return 1.f/(1.f + expf(-x)); }
// fast gate nonlinearities (gates only; loss path keeps libm). ~1e-7 abs error,
// compressed by the LSTM — vs 3.9e-3 absmax headroom.
__device__ __forceinline__ float sigm_fast(float x){ return 1.f/(1.f + __expf(-x)); }
__device__ __forceinline__ float tanh_fast(float x){
  float e = __expf(2.f*x);
  return 1.f - 2.f/(e + 1.f);
}

// split3 via HARDWARE bf16 RNE cvt (r9-verified). Self-correcting residuals.
__device__ __forceinline__ short bf_bits(__hip_bfloat16 b){
  union { __hip_bfloat16 b; short s; } u; u.b = b; return u.s;
}
__device__ __forceinline__ void split3(float x, short& h, short& m, short& l){
  __hip_bfloat16 bh = __float2bfloat16(x);
  h = bf_bits(bh);
  float r1 = x - __bfloat162float(bh);
  __hip_bfloat16 bm = __float2bfloat16(r1);
  m = bf_bits(bm);
  float r2 = r1 - __bfloat162float(bm);
  l = bf_bits(__float2bfloat16(r2));
}

// 6-term split-3 MFMA product (order matches r7-verified k_edge)
__device__ __forceinline__ f32x4 mfma6(bf16x8 aH, bf16x8 aM, bf16x8 aL,
                                       bf16x8 WH, bf16x8 WM, bf16x8 WL, f32x4 acc){
  acc = __builtin_amdgcn_mfma_f32_16x16x32_bf16(aH, WH, acc, 0,0,0);
  acc = __builtin_amdgcn_mfma_f32_16x16x32_bf16(aH, WM, acc, 0,0,0);
  acc = __builtin_amdgcn_mfma_f32_16x16x32_bf16(aM, WH, acc, 0,0,0);
  acc = __builtin_amdgcn_mfma_f32_16x16x32_bf16(aH, WL, acc, 0,0,0);
  acc = __builtin_amdgcn_mfma_f32_16x16x32_bf16(aL, WH, acc, 0,0,0);
  acc = __builtin_amdgcn_mfma_f32_16x16x32_bf16(aM, WM, acc, 0,0,0);
  return acc;
}

// Swapped-operand form: bitwise-identical accumulation, transposed D layout.
__device__ __forceinline__ f32x4 mfma6s(bf16x8 WH, bf16x8 WM, bf16x8 WL,
                                        bf16x8 aH, bf16x8 aM, bf16x8 aL, f32x4 acc){
  acc = __builtin_amdgcn_mfma_f32_16x16x32_bf16(WH, aH, acc, 0,0,0); // aH*WH
  acc = __builtin_amdgcn_mfma_f32_16x16x32_bf16(WM, aH, acc, 0,0,0); // aH*WM
  acc = __builtin_amdgcn_mfma_f32_16x16x32_bf16(WH, aM, acc, 0,0,0); // aM*WH
  acc = __builtin_amdgcn_mfma_f32_16x16x32_bf16(WL, aH, acc, 0,0,0); // aH*WL
  acc = __builtin_amdgcn_mfma_f32_16x16x32_bf16(WH, aL, acc, 0,0,0); // aL*WH
  acc = __builtin_amdgcn_mfma_f32_16x16x32_bf16(WM, aM, acc, 0,0,0); // aM*WM
  return acc;
}

// ---------- prep: weight transposes + loss zero ----------
__global__ void k_convert(float* ws, const float* msgW0, const float* Whh, const float* Wih,
                          const float* inW0, const float* inW)
{
  int i = blockIdx.x*256 + threadIdx.x;
  if (i < 9216){ int k=i/96, j=i%96; ws[O_W0AT+i] = msgW0[j*192+k];    return; } i -= 9216;
  if (i < 9216){ int k=i/96, j=i%96; ws[O_W0BT+i] = msgW0[j*192+96+k]; return; } i -= 9216;
  if (i < 36864){ int k=i/384, j=i%384; ws[O_WHHT+i]  = Whh[j*96+k];   return; } i -= 36864;
  if (i < 36864){ int k=i/384, j=i%384; ws[O_WIHXT+i] = Wih[j*192+k];  return; } i -= 36864;
  if (i < 4608){ int k=i/96, j=i%96; ws[O_WIN0T+i] = inW0[j*48+k];     return; } i -= 4608;
  if (i < 27648){ int l=i/9216, r=i%9216; int k=r/96, j=r%96;
                  ws[O_WINT+i] = inW[l*9216 + j*96 + k];               return; } i -= 27648;
  if (i == 0){ ws[O_LOSS] = 0.f; }
}

// ---------- msg W1/W2 -> bf16 split-3 B-fragments (edge kernel) ----------
__global__ void k_wfrag(float* ws, const float* msgW)
{
  int idx = blockIdx.x*256 + threadIdx.x;
  if (idx >= 2*3*18*64) return;
  int lane = idx & 63;
  int tile = (idx >> 6) % 18;
  int lev  = (idx >> 6) / 18 % 3;
  int layer= (idx >> 6) / 54;
  int nt = tile/3, kt = tile%3;
  int nout = (lane & 15) + 16*nt;
  int q = lane >> 4;
  unsigned short* wf = (unsigned short*)(ws + O_WFRAG);
  unsigned short* dstp = wf + (size_t)(((layer*3+lev)*18 + tile)*64 + lane)*8;
  const float* W = msgW + layer*9216;
  for (int j=0;j<8;j++){
    float wv = W[nout*96 + 32*kt + 8*q + j];
    short h,m,l; split3(wv, h, m, l);
    dstp[j] = (unsigned short)(lev==0 ? h : (lev==1 ? m : l));
  }
}

// ---------- Wcomb = W_ih[:,96:] @ msg_W[2]  (fold last msg layer into gates) ----------
__global__ void k_wcomb(float* ws, const float* Wih, const float* msgW, const float* msgb)
{
  int t = blockIdx.x*256 + threadIdx.x;
  if (t >= 36864) return;
  int j = t % 384, qq = t / 384;
  float a0=0.f,a1=0.f,a2=0.f,a3=0.f;
  for (int r=0;r<96;r+=4){
    a0 = fmaf(Wih[j*192+96+r  ], msgW[2*9216+(r  )*96+qq], a0);
    a1 = fmaf(Wih[j*192+96+r+1], msgW[2*9216+(r+1)*96+qq], a1);
    a2 = fmaf(Wih[j*192+96+r+2], msgW[2*9216+(r+2)*96+qq], a2);
    a3 = fmaf(Wih[j*192+96+r+3], msgW[2*9216+(r+3)*96+qq], a3);
  }
  ws[O_WCOMBT + qq*384 + j] = (a0+a1)+(a2+a3);
  if (qq == 0){
    float g=0.f;
    for (int r=0;r<96;r++) g = fmaf(Wih[j*192+96+r], msgb[288+r], g);
    ws[O_GB + j] = 20.f * g;
  }
}

// ---------- lstm gate weights [WC;WH] (K=192) -> bf16 split-3 B-fragments ----------
__global__ void k_wl(float* ws)
{
  int idx = blockIdx.x*256 + threadIdx.x;
  if (idx >= 24*6*64) return;
  int L  = idx & 63;
  int ks = (idx >> 6) % 6;
  int nt = (idx >> 6) / 6;
  int col = (L & 15) + 16*nt;
  int q = L >> 4;
  unsigned short* wf = (unsigned short*)(ws + O_WL2);
  for (int j=0;j<8;j++){
    int k = 32*(ks%3) + 8*q + j;
    float wv = (ks < 3) ? ws[O_WCOMBT + k*384 + col] : ws[O_WHHT + k*384 + col];
    short h,m,l; split3(wv, h, m, l);
    wf[(size_t)(((0*24+nt)*6 + ks)*64 + L)*8 + j] = (unsigned short)h;
    wf[(size_t)(((1*24+nt)*6 + ks)*64 + L)*8 + j] = (unsigned short)m;
    wf[(size_t)(((2*24+nt)*6 + ks)*64 + L)*8 + j] = (unsigned short)l;
  }
}

// ---------- A/B weights [W0A | W0B] (cols 0..191) -> bf16 split-3 B-fragments ----------
__global__ void k_wab(float* ws)
{
  int idx = blockIdx.x*256 + threadIdx.x;
  if (idx >= 12*3*64) return;
  int L  = idx & 63;
  int ks = (idx >> 6) % 3;
  int nt = (idx >> 6) / 3;
  int col = (L & 15) + 16*nt;
  int q = L >> 4;
  unsigned short* wf = (unsigned short*)(ws + O_WAB2);
  for (int j=0;j<8;j++){
    int k = 32*ks + 8*q + j;
    float wv = (col < 96) ? ws[O_W0AT + k*96 + col] : ws[O_W0BT + k*96 + (col-96)];
    short h,m,l; split3(wv, h, m, l);
    wf[(size_t)(((0*12+nt)*3 + ks)*64 + L)*8 + j] = (unsigned short)h;
    wf[(size_t)(((1*12+nt)*3 + ks)*64 + L)*8 + j] = (unsigned short)m;
    wf[(size_t)(((2*12+nt)*3 + ks)*64 + L)*8 + j] = (unsigned short)l;
  }
}

// ---------- input-MLP + W_ihx + outW weights -> split-3 frags ----------
__global__ void k_wfin(float* ws, const float* outW)
{
  int idx = blockIdx.x*256 + threadIdx.x;
  if (idx >= 141*64) return;
  int L = idx & 63;
  int f = idx >> 6;
  int q = L >> 4, mcol = L & 15;
  if (f < 12){
    int nt = f >> 1, ks = f & 1;
    int col = mcol + 16*nt;
    unsigned short* wp = (unsigned short*)(ws + SF_WIN0);
    for (int j=0;j<8;j++){
      int k = 32*ks + 8*q + j;
      float v = (k < 48) ? ws[O_WIN0T + k*96 + col] : 0.f;
      short h,m,l; split3(v,h,m,l);
      wp[(size_t)((0*12 + f)*64 + L)*8 + j] = (unsigned short)h;
      wp[(size_t)((1*12 + f)*64 + L)*8 + j] = (unsigned short)m;
      wp[(size_t)((2*12 + f)*64 + L)*8 + j] = (unsigned short)l;
    }
  } else if (f < 66){
    int f2 = f - 12;            // l*18 + nt*3 + ks
    int l = f2/18, r2 = f2%18;
    int nt = r2/3, ks = r2%3;
    int col = mcol + 16*nt;
    unsigned short* wp = (unsigned short*)(ws + SF_WIN);
    for (int j=0;j<8;j++){
      int k = 32*ks + 8*q + j;
      float v = ws[O_WINT + l*9216 + k*96 + col];
      short h,m,l2; split3(v,h,m,l2);
      wp[(size_t)((0*54 + f2)*64 + L)*8 + j] = (unsigned short)h;
      wp[(size_t)((1*54 + f2)*64 + L)*8 + j] = (unsigned short)m;
      wp[(size_t)((2*54 + f2)*64 + L)*8 + j] = (unsigned short)l2;
    }
  } else if (f < 138){
    int f3 = f - 66;            // nt*3 + ks, nt<24
    int nt = f3/3, ks = f3%3;
    int col = mcol + 16*nt;     // < 384
    unsigned short* wp = (unsigned short*)(ws + SF_WX);
    for (int j=0;j<8;j++){
      int k = 32*ks + 8*q + j;
      float v = ws[O_WIHXT + k*384 + col];
      short h,m,l2; split3(v,h,m,l2);
      wp[(size_t)((0*72 + f3)*64 + L)*8 + j] = (unsigned short)h;
      wp[(size_t)((1*72 + f3)*64 + L)*8 + j] = (unsigned short)m;
      wp[(size_t)((2*72 + f3)*64 + L)*8 + j] = (unsigned short)l2;
    }
  } else {
    int ks = f - 138;           // outW frags: col = class (0..9, pad), persistent
    unsigned short* wp = (unsigned short*)(ws + O_WO);
    for (int j=0;j<8;j++){
      int k = 32*ks + 8*q + j;
      float v = (mcol < 10) ? outW[mcol*96 + k] : 0.f;
      short h,m,l2; split3(v,h,m,l2);
      wp[(size_t)((0*3 + ks)*64 + L)*8 + j] = (unsigned short)h;
      wp[(size_t)((1*3 + ks)*64 + L)*8 + j] = (unsigned short)m;
      wp[(size_t)((2*3 + ks)*64 + L)*8 + j] = (unsigned short)l2;
    }
  }
}

// ---------- MFMA input MLP + fused step-0 A/B + fused gx, 16 nodes/block ----------
__global__ __launch_bounds__(384, 5) void k_input_mf(float* ws,
    const int* q, const int* row, const int* col,
    const float* demb, const float* remb, const float* cemb,
    const float* inb, const float* msgb)
{
  __shared__ float eintile[16*49];
  __shared__ bf16x8 fA[3][3][64];
  __shared__ bf16x8 fB[3][3][64];
  int tid = threadIdx.x;
  int w = tid >> 6, L = tid & 63;
  int m = L & 15, qd = L >> 4;
  int b2 = blockIdx.x; b2 = (b2 & 7)*81 + (b2 >> 3);   // XCD swizzle (648 = 8*81)
  int nb = b2*16;
  int colw = 16*w + m;

  // gather embeddings -> f32 tile
  for (int idx = tid; idx < 768; idx += 384){
    int ni = idx/48, f = idx%48;
    int n = nb + ni;
    float v;
    if (f < 16)      v = demb[q[n]*16 + f];
    else if (f < 32) v = remb[row[n]*16 + (f-16)];
    else             v = cemb[col[n]*16 + (f-32)];
    eintile[ni*49 + f] = v;
  }
  __syncthreads();

  // split3 ein -> fA (ks 0..1, K=48 zero-padded)
  if (tid < 128){
    int ks = tid >> 6, Ls = tid & 63;
    int node = Ls & 15, qs = Ls >> 4;
    bf16x8 vh, vm, vl;
    #pragma unroll
    for (int j=0;j<8;j++){
      int k = 32*ks + 8*qs + j;
      float v = (k < 48) ? eintile[node*49 + k] : 0.f;
      short hh,mm,ll; split3(v, hh, mm, ll);
      vh[j]=hh; vm[j]=mm; vl[j]=ll;
    }
    fA[0][ks][Ls]=vh; fA[1][ks][Ls]=vm; fA[2][ks][Ls]=vl;
  }
  __syncthreads();

  int kt = colw >> 5, qp = (colw & 31) >> 3, jc = colw & 7;

  // L0: read fA (2 ks), bias inb[colw], relu, scatter -> fB
  f32x4 acc;
  {
    float b0 = inb[colw];
    acc[0]=b0; acc[1]=b0; acc[2]=b0; acc[3]=b0;
    const bf16x8* W = (const bf16x8*)(ws + SF_WIN0);
    #pragma unroll
    for (int ks=0; ks<2; ks++){
      acc = mfma6(fA[0][ks][L], fA[1][ks][L], fA[2][ks][L],
                  W[(size_t)((0*12 + w*2+ks)*64) + L],
                  W[(size_t)((1*12 + w*2+ks)*64) + L],
                  W[(size_t)((2*12 + w*2+ks)*64) + L], acc);
    }
  }
  {
    unsigned short* bp = (unsigned short*)&fB[0][0][0];
    #pragma unroll
    for (int r=0;r<4;r++){
      float v = fmaxf(acc[r], 0.f);
      short hh,mm,ll; split3(v, hh, mm, ll);
      int Lp = 4*qd + r + 16*qp;
      bp[(size_t)((0*3+kt)*64 + Lp)*8 + jc] = (unsigned short)hh;
      bp[(size_t)((1*3+kt)*64 + Lp)*8 + jc] = (unsigned short)mm;
      bp[(size_t)((2*3+kt)*64 + Lp)*8 + jc] = (unsigned short)ll;
    }
  }
  __syncthreads();

  // L1..L3: alternate fB->fA->fB; bias inb[(l+1)*96+colw]; relu except last
  #pragma unroll
  for (int l=0; l<3; l++){
    bf16x8 (*src)[3][64] = (l & 1) ? fA : fB;
    bf16x8 (*dstb)[3][64] = (l & 1) ? fB : fA;
    float bl = inb[(l+1)*96 + colw];
    acc[0]=bl; acc[1]=bl; acc[2]=bl; acc[3]=bl;
    const bf16x8* W = (const bf16x8*)(ws + SF_WIN);
    #pragma unroll
    for (int ks=0; ks<3; ks++){
      acc = mfma6(src[0][ks][L], src[1][ks][L], src[2][ks][L],
                  W[(size_t)((0*54 + l*18 + w*3+ks)*64) + L],
                  W[(size_t)((1*54 + l*18 + w*3+ks)*64) + L],
                  W[(size_t)((2*54 + l*18 + w*3+ks)*64) + L], acc);
    }
    if (l < 2){
      unsigned short* bp = (unsigned short*)&dstb[0][0][0];
      #pragma unroll
      for (int r=0;r<4;r++){
        float v = fmaxf(acc[r], 0.f);
        short hh,mm,ll; split3(v, hh, mm, ll);
        int Lp = 4*qd + r + 16*qp;
        bp[(size_t)((0*3+kt)*64 + Lp)*8 + jc] = (unsigned short)hh;
        bp[(size_t)((1*3+kt)*64 + Lp)*8 + jc] = (unsigned short)mm;
        bp[(size_t)((2*3+kt)*64 + Lp)*8 + jc] = (unsigned short)ll;
      }
      __syncthreads();
    }
  }
  // final acc = h (no relu). write h, c=0; scatter h -> fA
  {
    unsigned short* bp = (unsigned short*)&fA[0][0][0];
    #pragma unroll
    for (int r=0;r<4;r++){
      int n = nb + 4*qd + r;
      ws[O_H + (size_t)n*96 + colw] = acc[r];
      ws[O_C + (size_t)n*96 + colw] = 0.f;
      short hh,mm,ll; split3(acc[r], hh, mm, ll);
      int Lp = 4*qd + r + 16*qp;
      bp[(size_t)((0*3+kt)*64 + Lp)*8 + jc] = (unsigned short)hh;
      bp[(size_t)((1*3+kt)*64 + Lp)*8 + jc] = (unsigned short)mm;
      bp[(size_t)((2*3+kt)*64 + Lp)*8 + jc] = (unsigned short)ll;
    }
  }
  __syncthreads();

  // A/B GEMM: wave w -> A cols nt=w, B cols nt=w+6
  {
    const bf16x8* wab = (const bf16x8*)(ws + O_WAB2);
    f32x4 accA = {0.f,0.f,0.f,0.f};
    f32x4 accB = {0.f,0.f,0.f,0.f};
    #pragma unroll
    for (int ks=0; ks<3; ks++){
      bf16x8 hH = fA[0][ks][L], hM = fA[1][ks][L], hL = fA[2][ks][L];
      accA = mfma6(hH, hM, hL,
                   wab[(size_t)(((0*12+w)*3 + ks)*64) + L],
                   wab[(size_t)(((1*12+w)*3 + ks)*64) + L],
                   wab[(size_t)(((2*12+w)*3 + ks)*64) + L], accA);
      accB = mfma6(hH, hM, hL,
                   wab[(size_t)(((0*12+w+6)*3 + ks)*64) + L],
                   wab[(size_t)(((1*12+w+6)*3 + ks)*64) + L],
                   wab[(size_t)(((2*12+w+6)*3 + ks)*64) + L], accB);
    }
    float b0v = msgb[colw];
    #pragma unroll
    for (int r=0; r<4; r++){
      int n = nb + 4*qd + r;
      ws[O_A  + (size_t)n*96 + colw] = accA[r];
      ws[O_BV + (size_t)n*96 + colw] = accB[r] + b0v;
    }
  }

  // gx GEMM: wave w -> cols nt=w+6g; store TRANSPOSED gx2[col][node] (f32x4 store)
  {
    const bf16x8* wx = (const bf16x8*)(ws + SF_WX);
    #pragma unroll
    for (int g=0; g<4; g++){
      int nt = w + 6*g;
      int c384 = m + 16*nt;
      float gbv = ws[O_GB + c384];
      f32x4 ag; ag[0]=gbv; ag[1]=gbv; ag[2]=gbv; ag[3]=gbv;
      #pragma unroll
      for (int ks=0; ks<3; ks++){
        ag = mfma6(fA[0][ks][L], fA[1][ks][L], fA[2][ks][L],
                   wx[(size_t)((0*72 + nt*3+ks)*64) + L],
                   wx[(size_t)((1*72 + nt*3+ks)*64) + L],
                   wx[(size_t)((2*72 + nt*3+ks)*64) + L], ag);
      }
      *(f32x4*)(ws + O_GX + (size_t)c384*NN + nb + 4*qd) = ag;
    }
  }
}

// ---------- fallback input MLP (j-parallel, f32; writes x for VALU lstm) ----------
__global__ __launch_bounds__(192) void k_input(float* ws,
    const int* q, const int* row, const int* col,
    const float* demb, const float* remb, const float* cemb,
    const float* inb, const float* msgb)
{
  __shared__ float ein[2][8*49];
  __shared__ float hb[2][8*97];
  int tid = threadIdx.x; int g = tid/96, j = tid%96;
  int nq = blockIdx.x*2 + g; int n0 = nq*8;

  for (int idx=j; idx<384; idx+=96){
    int i = idx/48, f = idx%48; int n = n0+i;
    float v;
    if (f < 16)      v = demb[q[n]*16 + f];
    else if (f < 32) v = remb[row[n]*16 + (f-16)];
    else             v = cemb[col[n]*16 + (f-32)];
    ein[g][i*49+f] = v;
  }
  __syncthreads();

  float acc[8];
  {
    const float* W0T = ws + O_WIN0T;
    float b0 = inb[j];
    #pragma unroll
    for (int i=0;i<8;i++) acc[i]=b0;
    #pragma unroll 2
    for (int k=0;k<48;k++){
      float w = W0T[k*96+j];
      #pragma unroll
      for (int i=0;i<8;i++) acc[i] = fmaf(w, ein[g][i*49+k], acc[i]);
    }
    #pragma unroll
    for (int i=0;i<8;i++) hb[g][i*97+j] = fmaxf(acc[i], 0.f);
  }
  __syncthreads();

  for (int l=0;l<3;l++){
    const float* WT = ws + O_WINT + l*9216;
    float bl = inb[(l+1)*96 + j];
    #pragma unroll
    for (int i=0;i<8;i++) acc[i]=bl;
    #pragma unroll 2
    for (int k=0;k<96;k++){
      float w = WT[k*96+j];
      #pragma unroll
      for (int i=0;i<8;i++) acc[i] = fmaf(w, hb[g][i*97+k], acc[i]);
    }
    __syncthreads();
    if (l < 2){
      #pragma unroll
      for (int i=0;i<8;i++) hb[g][i*97+j] = fmaxf(acc[i], 0.f);
    } else {
      #pragma unroll
      for (int i=0;i<8;i++) hb[g][i*97+j] = acc[i];
    }
    __syncthreads();
  }

  float* h = ws + O_H; float* c = ws + O_C; float* x = ws + O_X;
  #pragma unroll
  for (int i=0;i<8;i++){
    int n = n0+i;
    float vv = hb[g][i*97+j];
    h[n*96+j]=vv; x[n*96+j]=vv; c[n*96+j]=0.f;
  }
  const float* WA = ws + O_W0AT; const float* WB = ws + O_W0BT;
  float aa[8], ab[8];
  #pragma unroll
  for (int i=0;i<8;i++){ aa[i]=0.f; ab[i]=0.f; }
  #pragma unroll 2
  for (int k=0;k<96;k++){
    float wa=WA[k*96+j], wb=WB[k*96+j];
    #pragma unroll
    for (int i=0;i<8;i++){
      float hv = hb[g][i*97+k];
      aa[i]=fmaf(wa,hv,aa[i]); ab[i]=fmaf(wb,hv,ab[i]);
    }
  }
  float* A=ws+O_A; float* Bv=ws+O_BV;
  float b0v = msgb[j];
  #pragma unroll
  for (int i=0;i<8;i++){ int n=n0+i; A[n*96+j]=aa[i]; Bv[n*96+j]=ab[i]+b0v; }
}

// ---------- per-step edge MLP: column-parallel waves, 2 node-groups per block ----------
// grid 1296 (= EE/160); each block processes 2 consecutive 4-node groups with
// W1/W2 fragments + biases hoisted across the loop (halves L2 weight traffic and
// per-block setup). Swizzle sb=(b&7)*162+(b>>3) keeps edge/lstm XCD co-placement.
__global__ __launch_bounds__(384, 5) void k_edge(float* ws, const int* dst, const float* msgb)
{
  __shared__ bf16x8 aF[45][64];   // [lev*15 + mt*3 + kt][L], 46080 B
  int tid = threadIdx.x;
  int w = tid >> 6, L = tid & 63;
  int q = L >> 4, m = L & 15;
  int sb = blockIdx.x; sb = (sb & 7)*162 + (sb >> 3);   // 1296 = 8*162, bijective
  const unsigned short* wf = (const unsigned short*)(ws + O_WFRAG);
  const float* Aact = ws + O_A;
  const float* Bact = ws + O_BV;

  // hoisted: both layers' weight frags + biases (reused across both groups)
  bf16x8 W1[3][3], W2[3][3];
  #pragma unroll
  for (int lev=0; lev<3; lev++)
    #pragma unroll
    for (int kt2=0; kt2<3; kt2++){
      W1[lev][kt2] = ((const bf16x8*)wf)[(size_t)((0*3+lev)*18 + w*3+kt2)*64 + L];
      W2[lev][kt2] = ((const bf16x8*)wf)[(size_t)((1*3+lev)*18 + w*3+kt2)*64 + L];
    }
  float4 bb4 = *(const float4*)(msgb + 96 + 16*w + 4*q);
  float  bb2 = msgb[192 + 16*w + m];

  for (int grp=0; grp<2; ++grp){
    int bid = sb*2 + grp;
    int n0 = bid*4;
    int e0 = bid*80;

    // ---- phase A: r0 = relu(A[dst[e]] + B[n]); split3 -> aF ----
    for (int idx = tid; idx < 960; idx += 384){
      int mt = idx / 192;
      int kt = (idx % 192) / 64;
      int Ls = idx & 63;
      int el = mt*16 + (Ls & 15);
      int v  = dst[e0 + el];
      int n  = n0 + el/20;
      int k0 = 32*kt + 8*(Ls >> 4);
      float4 a0 = *(const float4*)(Aact + (size_t)v*96 + k0);
      float4 a1 = *(const float4*)(Aact + (size_t)v*96 + k0 + 4);
      float4 b0 = *(const float4*)(Bact + (size_t)n*96 + k0);
      float4 b1 = *(const float4*)(Bact + (size_t)n*96 + k0 + 4);
      float r[8];
      r[0]=fmaxf(a0.x+b0.x,0.f); r[1]=fmaxf(a0.y+b0.y,0.f);
      r[2]=fmaxf(a0.z+b0.z,0.f); r[3]=fmaxf(a0.w+b0.w,0.f);
      r[4]=fmaxf(a1.x+b1.x,0.f); r[5]=fmaxf(a1.y+b1.y,0.f);
      r[6]=fmaxf(a1.z+b1.z,0.f); r[7]=fmaxf(a1.w+b1.w,0.f);
      bf16x8 vh, vm, vl;
      #pragma unroll
      for (int j=0;j<8;j++){
        short hh,mm,ll; split3(r[j], hh, mm, ll);
        vh[j]=hh; vm[j]=mm; vl[j]=ll;
      }
      aF[0*15 + mt*3 + kt][Ls] = vh;
      aF[1*15 + mt*3 + kt][Ls] = vm;
      aF[2*15 + mt*3 + kt][Ls] = vl;
    }
    __syncthreads();

    // ---- phase B: layer-1 MFMA, swapped operands -> D[col][edge] ----
    f32x4 rD[5];
    #pragma unroll
    for (int nt=0; nt<5; nt++){
      f32x4 acc = {0.f,0.f,0.f,0.f};
      #pragma unroll
      for (int kt2=0; kt2<3; kt2++){
        acc = mfma6s(W1[0][kt2], W1[1][kt2], W1[2][kt2],
                     aF[0*15+nt*3+kt2][L], aF[1*15+nt*3+kt2][L], aF[2*15+nt*3+kt2][L],
                     acc);
      }
      rD[nt][0] = fmaxf(acc[0] + bb4.x, 0.f);
      rD[nt][1] = fmaxf(acc[1] + bb4.y, 0.f);
      rD[nt][2] = fmaxf(acc[2] + bb4.z, 0.f);
      rD[nt][3] = fmaxf(acc[3] + bb4.w, 0.f);
    }
    __syncthreads();   // all waves done reading aF before overwrite

    // ---- phase C: split3 + packed b64 scatter into layer-2 A-frags ----
    {
      int ktw = w >> 1;                 // = col>>5 for this wave's cols
      int qs  = 2*(w & 1) + (q >> 1);   // k-octet of col
      int Lp  = m + 16*qs;              // frag lane = (edge&15) + 16*qs
      int j0  = (q & 1)*4;              // ushort offset within lane chunk
      unsigned short* af16 = (unsigned short*)&aF[0][0];
      #pragma unroll
      for (int nt=0; nt<5; nt++){
        s16x4 vh4, vm4, vl4;
        #pragma unroll
        for (int r=0; r<4; r++){
          short hh,mm,ll; split3(rD[nt][r], hh, mm, ll);
          vh4[r]=hh; vm4[r]=mm; vl4[r]=ll;
        }
        *(s16x4*)(af16 + (size_t)((0*15+nt*3+ktw)*64 + Lp)*8 + j0) = vh4;
        *(s16x4*)(af16 + (size_t)((1*15+nt*3+ktw)*64 + Lp)*8 + j0) = vm4;
        *(s16x4*)(af16 + (size_t)((2*15+nt*3+ktw)*64 + Lp)*8 + j0) = vl4;
      }
    }
    __syncthreads();

    // ---- phase D: layer-2 MFMA + per-node aggregation -> s2 ----
    {
      float sn[4] = {0.f,0.f,0.f,0.f};
      #pragma unroll
      for (int mt=0; mt<5; mt++){
        f32x4 acc = {0.f,0.f,0.f,0.f};
        #pragma unroll
        for (int kt2=0; kt2<3; kt2++){
          acc = mfma6(aF[0*15+mt*3+kt2][L], aF[1*15+mt*3+kt2][L], aF[2*15+mt*3+kt2][L],
                      W2[0][kt2], W2[1][kt2], W2[2][kt2], acc);
        }
        #pragma unroll
        for (int r=0;r<4;r++){
          int el = mt*16 + 4*q + r;
          float o = fmaxf(acc[r] + bb2, 0.f);
          sn[el/20] += o;
        }
      }
      #pragma unroll
      for (int nd=0; nd<4; nd++){
        sn[nd] += __shfl_xor(sn[nd], 16);
        sn[nd] += __shfl_xor(sn[nd], 32);
      }
      if (L < 16){
        float* s2 = ws + O_S2;
        #pragma unroll
        for (int nd=0; nd<4; nd++)
          s2[(size_t)(n0+nd)*96 + 16*w + m] = sn[nd];
      }
    }
    __syncthreads();   // protect aF before next group's phase A
  }
}

// ---------- per-step LSTM via split-3 bf16 MFMA, 16 nodes/block ----------
__global__ __launch_bounds__(384, 5) void k_lstm_mf(float* ws, const int* labels,
                                                    const float* msgb,
                                                    const float* outW, const float* outb,
                                                    float* out, int t)
{
  __shared__ bf16x8 aF[3][384];
  __shared__ bf16x8 hF[3][192];
  __shared__ float sh2[16*100];
  __shared__ float lgt[256];
  int tid = threadIdx.x;
  int w = tid >> 6, L = tid & 63;
  int m = L & 15, q = L >> 4;
  int b2 = blockIdx.x; b2 = (b2 & 7)*81 + (b2 >> 3);   // XCD swizzle, matches k_edge
  int nb = b2*16;
  const float hscale = (t == 0) ? 0.f : 1.f;

  // early independent prefetches: c (used after main GEMM) and gx (acc init)
  float cpre[4];
  {
    int jj = m + 16*w;
    #pragma unroll
    for (int r=0; r<4; r++)
      cpre[r] = ws[O_C + (size_t)(nb + q*4 + r)*96 + jj];
  }
  f32x4 acc[4];
  #pragma unroll
  for (int g=0; g<4; g++){
    int c384 = m + 16*(w + 6*g);
    acc[g] = *(const f32x4*)(ws + O_GX + (size_t)c384*NN + nb + 4*q);
  }

  {
    int ks = tid/64; int Ls = tid%64;
    int node = nb + (Ls & 15); int qs = Ls >> 4;
    const float* src = (ks < 3) ? (ws + O_S2 + (size_t)node*96 + 32*ks + 8*qs)
                                : (ws + O_H  + (size_t)node*96 + 32*(ks-3) + 8*qs);
    float sc = (ks < 3) ? 1.f : hscale;
    float4 v0 = *(const float4*)src;
    float4 v1 = *(const float4*)(src + 4);
    float r[8] = {v0.x,v0.y,v0.z,v0.w,v1.x,v1.y,v1.z,v1.w};
    bf16x8 vh, vm, vl;
    #pragma unroll
    for (int j=0;j<8;j++){
      short hh,mm,ll; split3(r[j]*sc, hh, mm, ll);
      vh[j]=hh; vm[j]=mm; vl[j]=ll;
    }
    aF[0][tid]=vh; aF[1][tid]=vm; aF[2][tid]=vl;
  }
  __syncthreads();

  const bf16x8* wl = (const bf16x8*)(ws + O_WL2);
  #pragma unroll 2
  for (int ks=0; ks<6; ks++){
    bf16x8 aH = aF[0][ks*64+L], aM = aF[1][ks*64+L], aLw = aF[2][ks*64+L];
    #pragma unroll
    for (int g=0; g<4; g++){
      int nt = w + 6*g;
      bf16x8 WH = wl[(size_t)(((0*24+nt)*6 + ks)*64) + L];
      bf16x8 WM = wl[(size_t)(((1*24+nt)*6 + ks)*64) + L];
      bf16x8 WL = wl[(size_t)(((2*24+nt)*6 + ks)*64) + L];
      acc[g] = mfma6(aH, aM, aLw, WH, WM, WL, acc[g]);
    }
  }

  {
    int jj = m + 16*w;
    #pragma unroll
    for (int r=0; r<4; r++){
      int n = nb + q*4 + r;
      float ig = sigm_fast(acc[0][r]);
      float fg = sigm_fast(acc[1][r]);
      float gg = tanh_fast(acc[2][r]);
      float og = sigm_fast(acc[3][r]);
      float nc = fg*cpre[r] + ig*gg;
      float nv = og*tanh_fast(nc);
      ws[O_C + (size_t)n*96 + jj] = nc;
      ws[O_H + (size_t)n*96 + jj] = nv;
      sh2[(q*4 + r)*100 + jj] = nv;
    }
  }
  __syncthreads();

  // hF staging on all 384 threads (2 threads per frag slot, b64 halves)
  {
    int s = tid >> 1;                    // frag slot 0..191
    int ks = s/64, Ls = s%64, qs = Ls >> 4;
    int half = tid & 1;
    const float* src = &sh2[(Ls & 15)*100 + 32*ks + 8*qs + 4*half];
    float4 v0 = *(const float4*)src;
    s16x4 vh, vm, vl;
    float rr[4] = {v0.x, v0.y, v0.z, v0.w};
    #pragma unroll
    for (int j=0;j<4;j++){
      short hh,mm,ll; split3(rr[j], hh, mm, ll);
      vh[j]=hh; vm[j]=mm; vl[j]=ll;
    }
    unsigned short* hp0 = (unsigned short*)&hF[0][s];
    unsigned short* hp1 = (unsigned short*)&hF[1][s];
    unsigned short* hp2 = (unsigned short*)&hF[2][s];
    *(s16x4*)(hp0 + 4*half) = vh;
    *(s16x4*)(hp1 + 4*half) = vm;
    *(s16x4*)(hp2 + 4*half) = vl;
  }
  __syncthreads();

  {
    const bf16x8* wab = (const bf16x8*)(ws + O_WAB2);
    f32x4 accA = {0.f,0.f,0.f,0.f};
    f32x4 accB = {0.f,0.f,0.f,0.f};
    #pragma unroll
    for (int ks=0; ks<3; ks++){
      bf16x8 hH = hF[0][ks*64+L], hM = hF[1][ks*64+L], hLw = hF[2][ks*64+L];
      accA = mfma6(hH, hM, hLw,
                   wab[(size_t)(((0*12+w)*3 + ks)*64) + L],
                   wab[(size_t)(((1*12+w)*3 + ks)*64) + L],
                   wab[(size_t)(((2*12+w)*3 + ks)*64) + L], accA);
      accB = mfma6(hH, hM, hLw,
                   wab[(size_t)(((0*12+w+6)*3 + ks)*64) + L],
                   wab[(size_t)(((1*12+w+6)*3 + ks)*64) + L],
                   wab[(size_t)(((2*12+w+6)*3 + ks)*64) + L], accB);
    }
    int jj = m + 16*w;
    float b0v = msgb[jj];
    #pragma unroll
    for (int r=0; r<4; r++){
      int n = nb + q*4 + r;
      ws[O_A  + (size_t)n*96 + jj] = accA[r];
      ws[O_BV + (size_t)n*96 + jj] = accB[r] + b0v;
    }
  }

  // logits via MFMA on wave 0: D col = class (lane&15), row = node (q*4+r)
  if (w == 0){
    const bf16x8* wo = (const bf16x8*)(ws + O_WO);
    float ob = (m < 10) ? outb[m] : 0.f;
    f32x4 lacc; lacc[0]=ob; lacc[1]=ob; lacc[2]=ob; lacc[3]=ob;
    #pragma unroll
    for (int ks=0; ks<3; ks++){
      lacc = mfma6(hF[0][ks*64+L], hF[1][ks*64+L], hF[2][ks*64+L],
                   wo[(size_t)((0*3 + ks)*64) + L],
                   wo[(size_t)((1*3 + ks)*64) + L],
                   wo[(size_t)((2*3 + ks)*64) + L], lacc);
    }
    #pragma unroll
    for (int r=0; r<4; r++){
      int n = nb + 4*q + r;
      lgt[(4*q + r)*16 + m] = lacc[r];
      if (m < 10)
        out[165889 + ((size_t)t*NN + n)*10 + m] = lacc[r];
    }
  }
  __syncthreads();
  if (tid < 16){
    int n = nb + tid;
    const float* Lg = &lgt[tid*16];
    float mx = Lg[0]; int bi = 0;
    #pragma unroll
    for (int cc=1;cc<10;cc++){ if (Lg[cc] > mx){ mx=Lg[cc]; bi=cc; } }
    float se = 0.f;
    #pragma unroll
    for (int cc=0;cc<10;cc++) se += expf(Lg[cc]-mx);
    int lab = labels[n];
    float lp = Lg[lab] - mx - logf(se);
    atomicAdd(ws + O_LOSS, -lp);
    out[t*NN + n] = (float)bi;
  }
}

// ---------- fallback per-step LSTM (VALU, no gx needed) ----------
__global__ __launch_bounds__(384) void k_lstm_valu(float* ws, const int* labels,
                                                   const float* msgb,
                                                   const float* outW, const float* outb,
                                                   float* out, int t)
{
  __shared__ float ss[768], sh[768], sx[768];
  __shared__ float lg[8*384];
  __shared__ float lh[8*97];
  __shared__ float lgt[80];
  int tid = threadIdx.x;
  int nb = blockIdx.x*8;
  const float* WC = ws + O_WCOMBT;
  const float* WH = ws + O_WHHT;
  float* h = ws + O_H; float* c = ws + O_C;
  const float hscale = (t == 0) ? 0.f : 1.f;

  for (int idx = tid; idx < 768; idx += 384){
    ss[idx] = ws[O_S2 + (size_t)nb*96 + idx];
    sh[idx] = ws[O_H  + (size_t)nb*96 + idx] * hscale;
    sx[idx] = ws[O_X + (size_t)nb*96 + idx];
  }
  float acc[8];
  float gb = ws[O_GB + tid];
  #pragma unroll
  for (int i=0;i<8;i++) acc[i] = gb;
  __syncthreads();

  {
    const float* WX = ws + O_WIHXT;
    #pragma unroll 2
    for (int k0=0;k0<96;k0+=4){
      float4 xv[8];
      #pragma unroll
      for (int i=0;i<8;i++) xv[i] = *(const float4*)&sx[i*96+k0];
      #pragma unroll
      for (int kk=0;kk<4;kk++){
        float w = WX[(k0+kk)*384 + tid];
        #pragma unroll
        for (int i=0;i<8;i++){
          float xe = (kk==0)?xv[i].x:(kk==1)?xv[i].y:(kk==2)?xv[i].z:xv[i].w;
          acc[i] = fmaf(w, xe, acc[i]);
        }
      }
    }
  }

  #pragma unroll 2
  for (int k0=0;k0<96;k0+=4){
    float4 sv[8], rv[8];
    #pragma unroll
    for (int i=0;i<8;i++){
      sv[i] = *(const float4*)&ss[i*96+k0];
      rv[i] = *(const float4*)&sh[i*96+k0];
    }
    #pragma unroll
    for (int kk=0;kk<4;kk++){
      float cw = WC[(k0+kk)*384 + tid];
      float hw = WH[(k0+kk)*384 + tid];
      #pragma unroll
      for (int i=0;i<8;i++){
        float se = (kk==0)?sv[i].x:(kk==1)?sv[i].y:(kk==2)?sv[i].z:sv[i].w;
        float re = (kk==0)?rv[i].x:(kk==1)?rv[i].y:(kk==2)?rv[i].z:rv[i].w;
        acc[i] = fmaf(cw, se, fmaf(hw, re, acc[i]));
      }
    }
  }
  #pragma unroll
  for (int i=0;i<8;i++) lg[i*384 + tid] = acc[i];
  __syncthreads();

  #pragma unroll
  for (int half=0; half<2; half++){
    int p = tid + half*384;
    int i = p/96, jj = p%96;
    int n = nb + i;
    float ig = sigm(lg[i*384 + jj]);
    float fg = sigm(lg[i*384 + 96 + jj]);
    float gg = tanhf(lg[i*384 + 192 + jj]);
    float og = sigm(lg[i*384 + 288 + jj]);
    float cv = c[(size_t)n*96 + jj];
    float nc = fg*cv + ig*gg;
    float nv = og*tanhf(nc);
    c[(size_t)n*96 + jj] = nc;
    h[(size_t)n*96 + jj] = nv;
    lh[i*97 + jj] = nv;
  }
  __syncthreads();

  {
    const float* WA = ws + O_W0AT; const float* WB = ws + O_W0BT;
    int q3 = tid/96, jj = tid%96;
    int i0 = q3*2;
    float aa0=0.f, aa1=0.f, ab0=0.f, ab1=0.f;
    #pragma unroll 2
    for (int k=0;k<96;k++){
      float wa = WA[k*96+jj], wb = WB[k*96+jj];
      float h0v = lh[i0*97 + k], h1v = lh[(i0+1)*97 + k];
      aa0 = fmaf(wa, h0v, aa0); ab0 = fmaf(wb, h0v, ab0);
      aa1 = fmaf(wa, h1v, aa1); ab1 = fmaf(wb, h1v, ab1);
    }
    float b0v = msgb[jj];
    float* Aa = ws + O_A; float* Bb = ws + O_BV;
    Aa[(size_t)(nb+i0)*96 + jj]   = aa0; Bb[(size_t)(nb+i0)*96 + jj]   = ab0 + b0v;
    Aa[(size_t)(nb+i0+1)*96 + jj] = aa1; Bb[(size_t)(nb+i0+1)*96 + jj] = ab1 + b0v;
  }

  if (tid < 80){
    int ln = tid/10, cls = tid%10;
    int n = nb + ln;
    float q0=outb[cls], q1=0.f, q2=0.f, q3v=0.f;
    const float* hr = &lh[ln*97];
    #pragma unroll
    for (int k=0;k<96;k+=4){
      q0=fmaf(outW[cls*96+k  ],hr[k  ],q0);  q1=fmaf(outW[cls*96+k+1],hr[k+1],q1);
      q2=fmaf(outW[cls*96+k+2],hr[k+2],q2);  q3v=fmaf(outW[cls*96+k+3],hr[k+3],q3v);
    }
    float lgv = (q0+q1)+(q2+q3v);
    lgt[ln*10 + cls] = lgv;
    out[165889 + ((size_t)t*NN + n)*10 + cls] = lgv;
  }
  __syncthreads();
  if (tid < 8){
    int n = nb + tid;
    const float* Lg = &lgt[tid*10];
    float mx = Lg[0]; int bi = 0;
    #pragma unroll
    for (int cc=1;cc<10;cc++){ if (Lg[cc] > mx){ mx=Lg[cc]; bi=cc; } }
    float se = 0.f;
    #pragma unroll
    for (int cc=0;cc<10;cc++) se += expf(Lg[cc]-mx);
    int lab = labels[n];
    float lp = Lg[lab] - mx - logf(se);
    atomicAdd(ws + O_LOSS, -lp);
    out[t*NN + n] = (float)bi;
  }
}

__global__ void k_final(float* ws, float* out){
  if (threadIdx.x == 0 && blockIdx.x == 0)
    out[165888] = ws[O_LOSS] / (float)(TT*NN);
}

extern "C" void kernel_launch(void* const* d_in, const int* in_sizes, int n_in,
                              void* d_out, int out_size, void* d_ws, size_t ws_size,
                              hipStream_t stream)
{
  (void)in_sizes; (void)n_in; (void)out_size;
  const int* q      = (const int*)d_in[0];
  const int* row    = (const int*)d_in[1];
  const int* col    = (const int*)d_in[2];
  const int* labels = (const int*)d_in[3];
  const int* dst    = (const int*)d_in[5];
  const float* demb  = (const float*)d_in[6];
  const float* remb  = (const float*)d_in[7];
  const float* cemb  = (const float*)d_in[8];
  const float* inW0  = (const float*)d_in[9];
  const float* inW   = (const float*)d_in[10];
  const float* inb   = (const float*)d_in[11];
  const float* msgW0 = (const float*)d_in[12];
  const float* msgW  = (const float*)d_in[13];
  const float* msgb  = (const float*)d_in[14];
  const float* Wih   = (const float*)d_in[15];
  const float* Whh   = (const float*)d_in[16];
  const float* outW  = (const float*)d_in[17];
  const float* outb  = (const float*)d_in[18];

  float* ws  = (float*)d_ws;
  float* out = (float*)d_out;

  const size_t need_gx = ((size_t)O_GX + (size_t)NN*384) * sizeof(float);
  const int use_mf = (ws_size >= need_gx) ? 1 : 0;

  hipLaunchKernelGGL(k_convert, dim3(487), dim3(256), 0, stream,
                     ws, msgW0, Whh, Wih, inW0, inW);
  hipLaunchKernelGGL(k_wfrag, dim3(27), dim3(256), 0, stream, ws, msgW);
  hipLaunchKernelGGL(k_wcomb, dim3(144), dim3(256), 0, stream, ws, Wih, msgW, msgb);
  if (use_mf){
    hipLaunchKernelGGL(k_wfin, dim3(36), dim3(256), 0, stream, ws, outW);
    hipLaunchKernelGGL(k_wl,  dim3(36), dim3(256), 0, stream, ws);
    hipLaunchKernelGGL(k_wab, dim3(9),  dim3(256), 0, stream, ws);
    hipLaunchKernelGGL(k_input_mf, dim3(648), dim3(384), 0, stream,
                       ws, q, row, col, demb, remb, cemb, inb, msgb);
  } else {
    hipLaunchKernelGGL(k_input, dim3(648), dim3(192), 0, stream,
                       ws, q, row, col, demb, remb, cemb, inb, msgb);
  }
  for (int t=0; t<TT; ++t){
    hipLaunchKernelGGL(k_edge, dim3(EE/160), dim3(384), 0, stream, ws, dst, msgb);
    if (use_mf)
      hipLaunchKernelGGL(k_lstm_mf, dim3(NN/16), dim3(384), 0, stream,
                         ws, labels, msgb, outW, outb, out, t);
    else
      hipLaunchKernelGGL(k_lstm_valu, dim3(1296), dim3(384), 0, stream,
                         ws, labels, msgb, outW, outb, out, t);
  }
  hipLaunchKernelGGL(k_final, dim3(1), dim3(64), 0, stream, ws, out);
}

// Round 11
// 1526.707 us; speedup vs baseline: 1.3770x; 1.3770x over previous
//
#include <hip/hip_runtime.h>
#include <hip/hip_bf16.h>

#define NN 10368
#define EE 207360
#define TT 16

// ---- workspace layout (float offsets) ---- (r7-verified layout, 24.65 MB)
#define O_W0AT    0
#define O_W0BT    9216
#define O_WHHT    18432
#define O_WIHXT   55296
#define O_WCOMBT  92160
#define O_GB      129024
#define O_LOSS    129408
#define O_WIN0T   129424
#define O_WINT    134032
#define O_H       161680
#define O_C       (O_H  + NN*96)
#define O_A       (O_C  + NN*96)
#define O_BV      (O_A  + NN*96)
#define O_S2      (O_BV + NN*96)
#define O_X       (O_S2 + NN*96)
#define O_WFRAG   (O_X  + NN*96)   // ushort region: 2 layers x 3 levels x 18 tiles x 512 shorts
// OPTIONAL region — only used if ws_size is big enough (checked at launch):
#define O_GX      (O_WFRAG + 27648) // [384][NN] f32 TRANSPOSED: gb + W_ihx @ x, gx2[col][node]
// Overlay regions on O_X (MFMA path only; nothing writes O_X in that path):
#define O_WL2     O_X               // lstm gate-weight frags: 3 lev x 24 nt x 6 ks x 64 x 8 shorts
#define O_WAB2    (O_X + 110592)    // A/B weight frags: 3 lev x 12 nt x 3 ks x 64 x 8 shorts
#define O_WO      (O_X + 138240)    // outW frags: 3 lev x 3 ks x 64 x 8 shorts (persistent)
// Staging frags in O_S2 (free until first k_edge; consumed only by k_input_mf):
#define SF_WIN0   O_S2              // 3 lev x 6 nt x 2 ks frags (K=48 zero-padded)
#define SF_WIN    (O_S2 + 9216)     // 3 lev x 3 layer x 6 nt x 3 ks frags
#define SF_WX     (O_S2 + 50688)    // 3 lev x 24 nt x 3 ks frags (W_ihx)

using bf16x8 = __attribute__((ext_vector_type(8))) short;
using s16x4  = __attribute__((ext_vector_type(4))) short;
using f32x4  = __attribute__((ext_vector_type(4))) float;

__device__ __forceinline__ float sigm(float x){ return 1.f/(1.f + expf(-x)); }
// fast gate nonlinearities (gates only; loss path keeps libm). Validated r10:
// absmax unchanged at 0.00390625 with these in the 16-step recurrence.
__device__ __forceinline__ float sigm_fast(float x){ return 1.f/(1.f + __expf(-x)); }
__device__ __forceinline__ float tanh_fast(float x){
  float e = __expf(2.f*x);
  return 1.f - 2.f/(e + 1.f);
}

// split3 via HARDWARE bf16 RNE cvt (r9-verified). Self-correcting residuals.
__device__ __forceinline__ short bf_bits(__hip_bfloat16 b){
  union { __hip_bfloat16 b; short s; } u; u.b = b; return u.s;
}
__device__ __forceinline__ void split3(float x, short& h, short& m, short& l){
  __hip_bfloat16 bh = __float2bfloat16(x);
  h = bf_bits(bh);
  float r1 = x - __bfloat162float(bh);
  __hip_bfloat16 bm = __float2bfloat16(r1);
  m = bf_bits(bm);
  float r2 = r1 - __bfloat162float(bm);
  l = bf_bits(__float2bfloat16(r2));
}

// 6-term split-3 MFMA product (order matches r7-verified k_edge)
__device__ __forceinline__ f32x4 mfma6(bf16x8 aH, bf16x8 aM, bf16x8 aL,
                                       bf16x8 WH, bf16x8 WM, bf16x8 WL, f32x4 acc){
  acc = __builtin_amdgcn_mfma_f32_16x16x32_bf16(aH, WH, acc, 0,0,0);
  acc = __builtin_amdgcn_mfma_f32_16x16x32_bf16(aH, WM, acc, 0,0,0);
  acc = __builtin_amdgcn_mfma_f32_16x16x32_bf16(aM, WH, acc, 0,0,0);
  acc = __builtin_amdgcn_mfma_f32_16x16x32_bf16(aH, WL, acc, 0,0,0);
  acc = __builtin_amdgcn_mfma_f32_16x16x32_bf16(aL, WH, acc, 0,0,0);
  acc = __builtin_amdgcn_mfma_f32_16x16x32_bf16(aM, WM, acc, 0,0,0);
  return acc;
}

// Swapped-operand form: bitwise-identical accumulation, transposed D layout.
__device__ __forceinline__ f32x4 mfma6s(bf16x8 WH, bf16x8 WM, bf16x8 WL,
                                        bf16x8 aH, bf16x8 aM, bf16x8 aL, f32x4 acc){
  acc = __builtin_amdgcn_mfma_f32_16x16x32_bf16(WH, aH, acc, 0,0,0); // aH*WH
  acc = __builtin_amdgcn_mfma_f32_16x16x32_bf16(WM, aH, acc, 0,0,0); // aH*WM
  acc = __builtin_amdgcn_mfma_f32_16x16x32_bf16(WH, aM, acc, 0,0,0); // aM*WH
  acc = __builtin_amdgcn_mfma_f32_16x16x32_bf16(WL, aH, acc, 0,0,0); // aH*WL
  acc = __builtin_amdgcn_mfma_f32_16x16x32_bf16(WH, aL, acc, 0,0,0); // aL*WH
  acc = __builtin_amdgcn_mfma_f32_16x16x32_bf16(WM, aM, acc, 0,0,0); // aM*WM
  return acc;
}

// ---------- prep: weight transposes + loss zero ----------
__global__ void k_convert(float* ws, const float* msgW0, const float* Whh, const float* Wih,
                          const float* inW0, const float* inW)
{
  int i = blockIdx.x*256 + threadIdx.x;
  if (i < 9216){ int k=i/96, j=i%96; ws[O_W0AT+i] = msgW0[j*192+k];    return; } i -= 9216;
  if (i < 9216){ int k=i/96, j=i%96; ws[O_W0BT+i] = msgW0[j*192+96+k]; return; } i -= 9216;
  if (i < 36864){ int k=i/384, j=i%384; ws[O_WHHT+i]  = Whh[j*96+k];   return; } i -= 36864;
  if (i < 36864){ int k=i/384, j=i%384; ws[O_WIHXT+i] = Wih[j*192+k];  return; } i -= 36864;
  if (i < 4608){ int k=i/96, j=i%96; ws[O_WIN0T+i] = inW0[j*48+k];     return; } i -= 4608;
  if (i < 27648){ int l=i/9216, r=i%9216; int k=r/96, j=r%96;
                  ws[O_WINT+i] = inW[l*9216 + j*96 + k];               return; } i -= 27648;
  if (i == 0){ ws[O_LOSS] = 0.f; }
}

// ---------- msg W1/W2 -> bf16 split-3 B-fragments (edge kernel) ----------
__global__ void k_wfrag(float* ws, const float* msgW)
{
  int idx = blockIdx.x*256 + threadIdx.x;
  if (idx >= 2*3*18*64) return;
  int lane = idx & 63;
  int tile = (idx >> 6) % 18;
  int lev  = (idx >> 6) / 18 % 3;
  int layer= (idx >> 6) / 54;
  int nt = tile/3, kt = tile%3;
  int nout = (lane & 15) + 16*nt;
  int q = lane >> 4;
  unsigned short* wf = (unsigned short*)(ws + O_WFRAG);
  unsigned short* dstp = wf + (size_t)(((layer*3+lev)*18 + tile)*64 + lane)*8;
  const float* W = msgW + layer*9216;
  for (int j=0;j<8;j++){
    float wv = W[nout*96 + 32*kt + 8*q + j];
    short h,m,l; split3(wv, h, m, l);
    dstp[j] = (unsigned short)(lev==0 ? h : (lev==1 ? m : l));
  }
}

// ---------- Wcomb = W_ih[:,96:] @ msg_W[2]  (fold last msg layer into gates) ----------
__global__ void k_wcomb(float* ws, const float* Wih, const float* msgW, const float* msgb)
{
  int t = blockIdx.x*256 + threadIdx.x;
  if (t >= 36864) return;
  int j = t % 384, qq = t / 384;
  float a0=0.f,a1=0.f,a2=0.f,a3=0.f;
  for (int r=0;r<96;r+=4){
    a0 = fmaf(Wih[j*192+96+r  ], msgW[2*9216+(r  )*96+qq], a0);
    a1 = fmaf(Wih[j*192+96+r+1], msgW[2*9216+(r+1)*96+qq], a1);
    a2 = fmaf(Wih[j*192+96+r+2], msgW[2*9216+(r+2)*96+qq], a2);
    a3 = fmaf(Wih[j*192+96+r+3], msgW[2*9216+(r+3)*96+qq], a3);
  }
  ws[O_WCOMBT + qq*384 + j] = (a0+a1)+(a2+a3);
  if (qq == 0){
    float g=0.f;
    for (int r=0;r<96;r++) g = fmaf(Wih[j*192+96+r], msgb[288+r], g);
    ws[O_GB + j] = 20.f * g;
  }
}

// ---------- lstm gate weights [WC;WH] (K=192) -> bf16 split-3 B-fragments ----------
__global__ void k_wl(float* ws)
{
  int idx = blockIdx.x*256 + threadIdx.x;
  if (idx >= 24*6*64) return;
  int L  = idx & 63;
  int ks = (idx >> 6) % 6;
  int nt = (idx >> 6) / 6;
  int col = (L & 15) + 16*nt;
  int q = L >> 4;
  unsigned short* wf = (unsigned short*)(ws + O_WL2);
  for (int j=0;j<8;j++){
    int k = 32*(ks%3) + 8*q + j;
    float wv = (ks < 3) ? ws[O_WCOMBT + k*384 + col] : ws[O_WHHT + k*384 + col];
    short h,m,l; split3(wv, h, m, l);
    wf[(size_t)(((0*24+nt)*6 + ks)*64 + L)*8 + j] = (unsigned short)h;
    wf[(size_t)(((1*24+nt)*6 + ks)*64 + L)*8 + j] = (unsigned short)m;
    wf[(size_t)(((2*24+nt)*6 + ks)*64 + L)*8 + j] = (unsigned short)l;
  }
}

// ---------- A/B weights [W0A | W0B] (cols 0..191) -> bf16 split-3 B-fragments ----------
__global__ void k_wab(float* ws)
{
  int idx = blockIdx.x*256 + threadIdx.x;
  if (idx >= 12*3*64) return;
  int L  = idx & 63;
  int ks = (idx >> 6) % 3;
  int nt = (idx >> 6) / 3;
  int col = (L & 15) + 16*nt;
  int q = L >> 4;
  unsigned short* wf = (unsigned short*)(ws + O_WAB2);
  for (int j=0;j<8;j++){
    int k = 32*ks + 8*q + j;
    float wv = (col < 96) ? ws[O_W0AT + k*96 + col] : ws[O_W0BT + k*96 + (col-96)];
    short h,m,l; split3(wv, h, m, l);
    wf[(size_t)(((0*12+nt)*3 + ks)*64 + L)*8 + j] = (unsigned short)h;
    wf[(size_t)(((1*12+nt)*3 + ks)*64 + L)*8 + j] = (unsigned short)m;
    wf[(size_t)(((2*12+nt)*3 + ks)*64 + L)*8 + j] = (unsigned short)l;
  }
}

// ---------- input-MLP + W_ihx + outW weights -> split-3 frags ----------
__global__ void k_wfin(float* ws, const float* outW)
{
  int idx = blockIdx.x*256 + threadIdx.x;
  if (idx >= 141*64) return;
  int L = idx & 63;
  int f = idx >> 6;
  int q = L >> 4, mcol = L & 15;
  if (f < 12){
    int nt = f >> 1, ks = f & 1;
    int col = mcol + 16*nt;
    unsigned short* wp = (unsigned short*)(ws + SF_WIN0);
    for (int j=0;j<8;j++){
      int k = 32*ks + 8*q + j;
      float v = (k < 48) ? ws[O_WIN0T + k*96 + col] : 0.f;
      short h,m,l; split3(v,h,m,l);
      wp[(size_t)((0*12 + f)*64 + L)*8 + j] = (unsigned short)h;
      wp[(size_t)((1*12 + f)*64 + L)*8 + j] = (unsigned short)m;
      wp[(size_t)((2*12 + f)*64 + L)*8 + j] = (unsigned short)l;
    }
  } else if (f < 66){
    int f2 = f - 12;            // l*18 + nt*3 + ks
    int l = f2/18, r2 = f2%18;
    int nt = r2/3, ks = r2%3;
    int col = mcol + 16*nt;
    unsigned short* wp = (unsigned short*)(ws + SF_WIN);
    for (int j=0;j<8;j++){
      int k = 32*ks + 8*q + j;
      float v = ws[O_WINT + l*9216 + k*96 + col];
      short h,m,l2; split3(v,h,m,l2);
      wp[(size_t)((0*54 + f2)*64 + L)*8 + j] = (unsigned short)h;
      wp[(size_t)((1*54 + f2)*64 + L)*8 + j] = (unsigned short)m;
      wp[(size_t)((2*54 + f2)*64 + L)*8 + j] = (unsigned short)l2;
    }
  } else if (f < 138){
    int f3 = f - 66;            // nt*3 + ks, nt<24
    int nt = f3/3, ks = f3%3;
    int col = mcol + 16*nt;     // < 384
    unsigned short* wp = (unsigned short*)(ws + SF_WX);
    for (int j=0;j<8;j++){
      int k = 32*ks + 8*q + j;
      float v = ws[O_WIHXT + k*384 + col];
      short h,m,l2; split3(v,h,m,l2);
      wp[(size_t)((0*72 + f3)*64 + L)*8 + j] = (unsigned short)h;
      wp[(size_t)((1*72 + f3)*64 + L)*8 + j] = (unsigned short)m;
      wp[(size_t)((2*72 + f3)*64 + L)*8 + j] = (unsigned short)l2;
    }
  } else {
    int ks = f - 138;           // outW frags: col = class (0..9, pad), persistent
    unsigned short* wp = (unsigned short*)(ws + O_WO);
    for (int j=0;j<8;j++){
      int k = 32*ks + 8*q + j;
      float v = (mcol < 10) ? outW[mcol*96 + k] : 0.f;
      short h,m,l2; split3(v,h,m,l2);
      wp[(size_t)((0*3 + ks)*64 + L)*8 + j] = (unsigned short)h;
      wp[(size_t)((1*3 + ks)*64 + L)*8 + j] = (unsigned short)m;
      wp[(size_t)((2*3 + ks)*64 + L)*8 + j] = (unsigned short)l2;
    }
  }
}

// ---------- MFMA input MLP + fused step-0 A/B + fused gx, 16 nodes/block ----------
__global__ __launch_bounds__(384, 5) void k_input_mf(float* ws,
    const int* q, const int* row, const int* col,
    const float* demb, const float* remb, const float* cemb,
    const float* inb, const float* msgb)
{
  __shared__ float eintile[16*49];
  __shared__ bf16x8 fA[3][3][64];
  __shared__ bf16x8 fB[3][3][64];
  int tid = threadIdx.x;
  int w = tid >> 6, L = tid & 63;
  int m = L & 15, qd = L >> 4;
  int b2 = blockIdx.x; b2 = (b2 & 7)*81 + (b2 >> 3);   // XCD swizzle (648 = 8*81)
  int nb = b2*16;
  int colw = 16*w + m;

  // gather embeddings -> f32 tile
  for (int idx = tid; idx < 768; idx += 384){
    int ni = idx/48, f = idx%48;
    int n = nb + ni;
    float v;
    if (f < 16)      v = demb[q[n]*16 + f];
    else if (f < 32) v = remb[row[n]*16 + (f-16)];
    else             v = cemb[col[n]*16 + (f-32)];
    eintile[ni*49 + f] = v;
  }
  __syncthreads();

  // split3 ein -> fA (ks 0..1, K=48 zero-padded)
  if (tid < 128){
    int ks = tid >> 6, Ls = tid & 63;
    int node = Ls & 15, qs = Ls >> 4;
    bf16x8 vh, vm, vl;
    #pragma unroll
    for (int j=0;j<8;j++){
      int k = 32*ks + 8*qs + j;
      float v = (k < 48) ? eintile[node*49 + k] : 0.f;
      short hh,mm,ll; split3(v, hh, mm, ll);
      vh[j]=hh; vm[j]=mm; vl[j]=ll;
    }
    fA[0][ks][Ls]=vh; fA[1][ks][Ls]=vm; fA[2][ks][Ls]=vl;
  }
  __syncthreads();

  int kt = colw >> 5, qp = (colw & 31) >> 3, jc = colw & 7;

  // L0: read fA (2 ks), bias inb[colw], relu, scatter -> fB
  f32x4 acc;
  {
    float b0 = inb[colw];
    acc[0]=b0; acc[1]=b0; acc[2]=b0; acc[3]=b0;
    const bf16x8* W = (const bf16x8*)(ws + SF_WIN0);
    #pragma unroll
    for (int ks=0; ks<2; ks++){
      acc = mfma6(fA[0][ks][L], fA[1][ks][L], fA[2][ks][L],
                  W[(size_t)((0*12 + w*2+ks)*64) + L],
                  W[(size_t)((1*12 + w*2+ks)*64) + L],
                  W[(size_t)((2*12 + w*2+ks)*64) + L], acc);
    }
  }
  {
    unsigned short* bp = (unsigned short*)&fB[0][0][0];
    #pragma unroll
    for (int r=0;r<4;r++){
      float v = fmaxf(acc[r], 0.f);
      short hh,mm,ll; split3(v, hh, mm, ll);
      int Lp = 4*qd + r + 16*qp;
      bp[(size_t)((0*3+kt)*64 + Lp)*8 + jc] = (unsigned short)hh;
      bp[(size_t)((1*3+kt)*64 + Lp)*8 + jc] = (unsigned short)mm;
      bp[(size_t)((2*3+kt)*64 + Lp)*8 + jc] = (unsigned short)ll;
    }
  }
  __syncthreads();

  // L1..L3: alternate fB->fA->fB; bias inb[(l+1)*96+colw]; relu except last
  #pragma unroll
  for (int l=0; l<3; l++){
    bf16x8 (*src)[3][64] = (l & 1) ? fA : fB;
    bf16x8 (*dstb)[3][64] = (l & 1) ? fB : fA;
    float bl = inb[(l+1)*96 + colw];
    acc[0]=bl; acc[1]=bl; acc[2]=bl; acc[3]=bl;
    const bf16x8* W = (const bf16x8*)(ws + SF_WIN);
    #pragma unroll
    for (int ks=0; ks<3; ks++){
      acc = mfma6(src[0][ks][L], src[1][ks][L], src[2][ks][L],
                  W[(size_t)((0*54 + l*18 + w*3+ks)*64) + L],
                  W[(size_t)((1*54 + l*18 + w*3+ks)*64) + L],
                  W[(size_t)((2*54 + l*18 + w*3+ks)*64) + L], acc);
    }
    if (l < 2){
      unsigned short* bp = (unsigned short*)&dstb[0][0][0];
      #pragma unroll
      for (int r=0;r<4;r++){
        float v = fmaxf(acc[r], 0.f);
        short hh,mm,ll; split3(v, hh, mm, ll);
        int Lp = 4*qd + r + 16*qp;
        bp[(size_t)((0*3+kt)*64 + Lp)*8 + jc] = (unsigned short)hh;
        bp[(size_t)((1*3+kt)*64 + Lp)*8 + jc] = (unsigned short)mm;
        bp[(size_t)((2*3+kt)*64 + Lp)*8 + jc] = (unsigned short)ll;
      }
      __syncthreads();
    }
  }
  // final acc = h (no relu). write h, c=0; scatter h -> fA
  {
    unsigned short* bp = (unsigned short*)&fA[0][0][0];
    #pragma unroll
    for (int r=0;r<4;r++){
      int n = nb + 4*qd + r;
      ws[O_H + (size_t)n*96 + colw] = acc[r];
      ws[O_C + (size_t)n*96 + colw] = 0.f;
      short hh,mm,ll; split3(acc[r], hh, mm, ll);
      int Lp = 4*qd + r + 16*qp;
      bp[(size_t)((0*3+kt)*64 + Lp)*8 + jc] = (unsigned short)hh;
      bp[(size_t)((1*3+kt)*64 + Lp)*8 + jc] = (unsigned short)mm;
      bp[(size_t)((2*3+kt)*64 + Lp)*8 + jc] = (unsigned short)ll;
    }
  }
  __syncthreads();

  // A/B GEMM: wave w -> A cols nt=w, B cols nt=w+6
  {
    const bf16x8* wab = (const bf16x8*)(ws + O_WAB2);
    f32x4 accA = {0.f,0.f,0.f,0.f};
    f32x4 accB = {0.f,0.f,0.f,0.f};
    #pragma unroll
    for (int ks=0; ks<3; ks++){
      bf16x8 hH = fA[0][ks][L], hM = fA[1][ks][L], hL = fA[2][ks][L];
      accA = mfma6(hH, hM, hL,
                   wab[(size_t)(((0*12+w)*3 + ks)*64) + L],
                   wab[(size_t)(((1*12+w)*3 + ks)*64) + L],
                   wab[(size_t)(((2*12+w)*3 + ks)*64) + L], accA);
      accB = mfma6(hH, hM, hL,
                   wab[(size_t)(((0*12+w+6)*3 + ks)*64) + L],
                   wab[(size_t)(((1*12+w+6)*3 + ks)*64) + L],
                   wab[(size_t)(((2*12+w+6)*3 + ks)*64) + L], accB);
    }
    float b0v = msgb[colw];
    #pragma unroll
    for (int r=0; r<4; r++){
      int n = nb + 4*qd + r;
      ws[O_A  + (size_t)n*96 + colw] = accA[r];
      ws[O_BV + (size_t)n*96 + colw] = accB[r] + b0v;
    }
  }

  // gx GEMM: wave w -> cols nt=w+6g; store TRANSPOSED gx2[col][node] (f32x4 store)
  {
    const bf16x8* wx = (const bf16x8*)(ws + SF_WX);
    #pragma unroll
    for (int g=0; g<4; g++){
      int nt = w + 6*g;
      int c384 = m + 16*nt;
      float gbv = ws[O_GB + c384];
      f32x4 ag; ag[0]=gbv; ag[1]=gbv; ag[2]=gbv; ag[3]=gbv;
      #pragma unroll
      for (int ks=0; ks<3; ks++){
        ag = mfma6(fA[0][ks][L], fA[1][ks][L], fA[2][ks][L],
                   wx[(size_t)((0*72 + nt*3+ks)*64) + L],
                   wx[(size_t)((1*72 + nt*3+ks)*64) + L],
                   wx[(size_t)((2*72 + nt*3+ks)*64) + L], ag);
      }
      *(f32x4*)(ws + O_GX + (size_t)c384*NN + nb + 4*qd) = ag;
    }
  }
}

// ---------- fallback input MLP (j-parallel, f32; writes x for VALU lstm) ----------
__global__ __launch_bounds__(192) void k_input(float* ws,
    const int* q, const int* row, const int* col,
    const float* demb, const float* remb, const float* cemb,
    const float* inb, const float* msgb)
{
  __shared__ float ein[2][8*49];
  __shared__ float hb[2][8*97];
  int tid = threadIdx.x; int g = tid/96, j = tid%96;
  int nq = blockIdx.x*2 + g; int n0 = nq*8;

  for (int idx=j; idx<384; idx+=96){
    int i = idx/48, f = idx%48; int n = n0+i;
    float v;
    if (f < 16)      v = demb[q[n]*16 + f];
    else if (f < 32) v = remb[row[n]*16 + (f-16)];
    else             v = cemb[col[n]*16 + (f-32)];
    ein[g][i*49+f] = v;
  }
  __syncthreads();

  float acc[8];
  {
    const float* W0T = ws + O_WIN0T;
    float b0 = inb[j];
    #pragma unroll
    for (int i=0;i<8;i++) acc[i]=b0;
    #pragma unroll 2
    for (int k=0;k<48;k++){
      float w = W0T[k*96+j];
      #pragma unroll
      for (int i=0;i<8;i++) acc[i] = fmaf(w, ein[g][i*49+k], acc[i]);
    }
    #pragma unroll
    for (int i=0;i<8;i++) hb[g][i*97+j] = fmaxf(acc[i], 0.f);
  }
  __syncthreads();

  for (int l=0;l<3;l++){
    const float* WT = ws + O_WINT + l*9216;
    float bl = inb[(l+1)*96 + j];
    #pragma unroll
    for (int i=0;i<8;i++) acc[i]=bl;
    #pragma unroll 2
    for (int k=0;k<96;k++){
      float w = WT[k*96+j];
      #pragma unroll
      for (int i=0;i<8;i++) acc[i] = fmaf(w, hb[g][i*97+k], acc[i]);
    }
    __syncthreads();
    if (l < 2){
      #pragma unroll
      for (int i=0;i<8;i++) hb[g][i*97+j] = fmaxf(acc[i], 0.f);
    } else {
      #pragma unroll
      for (int i=0;i<8;i++) hb[g][i*97+j] = acc[i];
    }
    __syncthreads();
  }

  float* h = ws + O_H; float* c = ws + O_C; float* x = ws + O_X;
  #pragma unroll
  for (int i=0;i<8;i++){
    int n = n0+i;
    float vv = hb[g][i*97+j];
    h[n*96+j]=vv; x[n*96+j]=vv; c[n*96+j]=0.f;
  }
  const float* WA = ws + O_W0AT; const float* WB = ws + O_W0BT;
  float aa[8], ab[8];
  #pragma unroll
  for (int i=0;i<8;i++){ aa[i]=0.f; ab[i]=0.f; }
  #pragma unroll 2
  for (int k=0;k<96;k++){
    float wa=WA[k*96+j], wb=WB[k*96+j];
    #pragma unroll
    for (int i=0;i<8;i++){
      float hv = hb[g][i*97+k];
      aa[i]=fmaf(wa,hv,aa[i]); ab[i]=fmaf(wb,hv,ab[i]);
    }
  }
  float* A=ws+O_A; float* Bv=ws+O_BV;
  float b0v = msgb[j];
  #pragma unroll
  for (int i=0;i<8;i++){ int n=n0+i; A[n*96+j]=aa[i]; Bv[n*96+j]=ab[i]+b0v; }
}

// ---------- per-step edge MLP: column-parallel waves (r9-verified 58us version) ----------
// Single group per block (grid 2592). W1 prefetched before the phase-A barrier,
// W2 during phase C — short sequential live ranges, no spill (r10's 2-group loop
// widened the live set and spilled 97MB/dispatch to scratch).
__global__ __launch_bounds__(384, 5) void k_edge(float* ws, const int* dst, const float* msgb)
{
  __shared__ bf16x8 aF[45][64];   // [lev*15 + mt*3 + kt][L], 46080 B
  int tid = threadIdx.x;
  int w = tid >> 6, L = tid & 63;
  int q = L >> 4, m = L & 15;
  int g4 = blockIdx.x >> 2;
  g4 = (g4 & 7)*81 + (g4 >> 3);                  // 648 groups = 8*81, bijective
  int bid = g4*4 + (blockIdx.x & 3);
  int n0 = bid*4;
  int e0 = bid*80;
  const unsigned short* wf = (const unsigned short*)(ws + O_WFRAG);
  const float* Aact = ws + O_A;
  const float* Bact = ws + O_BV;

  // ---- phase A: r0 = relu(A[dst[e]] + B[n]); split3 -> aF ----
  for (int idx = tid; idx < 960; idx += 384){
    int mt = idx / 192;
    int kt = (idx % 192) / 64;
    int Ls = idx & 63;
    int el = mt*16 + (Ls & 15);
    int v  = dst[e0 + el];
    int n  = n0 + el/20;
    int k0 = 32*kt + 8*(Ls >> 4);
    float4 a0 = *(const float4*)(Aact + (size_t)v*96 + k0);
    float4 a1 = *(const float4*)(Aact + (size_t)v*96 + k0 + 4);
    float4 b0 = *(const float4*)(Bact + (size_t)n*96 + k0);
    float4 b1 = *(const float4*)(Bact + (size_t)n*96 + k0 + 4);
    float r[8];
    r[0]=fmaxf(a0.x+b0.x,0.f); r[1]=fmaxf(a0.y+b0.y,0.f);
    r[2]=fmaxf(a0.z+b0.z,0.f); r[3]=fmaxf(a0.w+b0.w,0.f);
    r[4]=fmaxf(a1.x+b1.x,0.f); r[5]=fmaxf(a1.y+b1.y,0.f);
    r[6]=fmaxf(a1.z+b1.z,0.f); r[7]=fmaxf(a1.w+b1.w,0.f);
    bf16x8 vh, vm, vl;
    #pragma unroll
    for (int j=0;j<8;j++){
      short hh,mm,ll; split3(r[j], hh, mm, ll);
      vh[j]=hh; vm[j]=mm; vl[j]=ll;
    }
    aF[0*15 + mt*3 + kt][Ls] = vh;
    aF[1*15 + mt*3 + kt][Ls] = vm;
    aF[2*15 + mt*3 + kt][Ls] = vl;
  }

  // prefetch W1 (layer-1 weight frags) while phase A drains / before barrier
  bf16x8 W1[3][3];
  #pragma unroll
  for (int lev=0; lev<3; lev++)
    #pragma unroll
    for (int kt2=0; kt2<3; kt2++)
      W1[lev][kt2] = ((const bf16x8*)wf)[(size_t)((0*3+lev)*18 + w*3+kt2)*64 + L];
  __syncthreads();

  // ---- phase B: layer-1 MFMA, swapped operands -> D[col][edge] ----
  f32x4 rD[5];
  {
    float4 bb4 = *(const float4*)(msgb + 96 + 16*w + 4*q);
    #pragma unroll
    for (int nt=0; nt<5; nt++){
      f32x4 acc = {0.f,0.f,0.f,0.f};
      #pragma unroll
      for (int kt2=0; kt2<3; kt2++){
        acc = mfma6s(W1[0][kt2], W1[1][kt2], W1[2][kt2],
                     aF[0*15+nt*3+kt2][L], aF[1*15+nt*3+kt2][L], aF[2*15+nt*3+kt2][L],
                     acc);
      }
      rD[nt][0] = fmaxf(acc[0] + bb4.x, 0.f);
      rD[nt][1] = fmaxf(acc[1] + bb4.y, 0.f);
      rD[nt][2] = fmaxf(acc[2] + bb4.z, 0.f);
      rD[nt][3] = fmaxf(acc[3] + bb4.w, 0.f);
    }
  }
  __syncthreads();   // all waves done reading aF before overwrite

  // prefetch W2 (layer-2 weight frags) — latency hides under phase C VALU
  bf16x8 W2[3][3];
  #pragma unroll
  for (int lev=0; lev<3; lev++)
    #pragma unroll
    for (int kt2=0; kt2<3; kt2++)
      W2[lev][kt2] = ((const bf16x8*)wf)[(size_t)((1*3+lev)*18 + w*3+kt2)*64 + L];

  // ---- phase C: split3 + packed b64 scatter into layer-2 A-frags ----
  {
    int ktw = w >> 1;                 // = col>>5 for this wave's cols
    int qs  = 2*(w & 1) + (q >> 1);   // k-octet of col
    int Lp  = m + 16*qs;              // frag lane = (edge&15) + 16*qs
    int j0  = (q & 1)*4;              // ushort offset within lane chunk
    unsigned short* af16 = (unsigned short*)&aF[0][0];
    #pragma unroll
    for (int nt=0; nt<5; nt++){
      s16x4 vh4, vm4, vl4;
      #pragma unroll
      for (int r=0; r<4; r++){
        short hh,mm,ll; split3(rD[nt][r], hh, mm, ll);
        vh4[r]=hh; vm4[r]=mm; vl4[r]=ll;
      }
      *(s16x4*)(af16 + (size_t)((0*15+nt*3+ktw)*64 + Lp)*8 + j0) = vh4;
      *(s16x4*)(af16 + (size_t)((1*15+nt*3+ktw)*64 + Lp)*8 + j0) = vm4;
      *(s16x4*)(af16 + (size_t)((2*15+nt*3+ktw)*64 + Lp)*8 + j0) = vl4;
    }
  }
  __syncthreads();

  // ---- phase D: layer-2 MFMA + per-node aggregation -> s2 ----
  {
    float bb = msgb[192 + 16*w + m];
    float sn[4] = {0.f,0.f,0.f,0.f};
    #pragma unroll
    for (int mt=0; mt<5; mt++){
      f32x4 acc = {0.f,0.f,0.f,0.f};
      #pragma unroll
      for (int kt2=0; kt2<3; kt2++){
        acc = mfma6(aF[0*15+mt*3+kt2][L], aF[1*15+mt*3+kt2][L], aF[2*15+mt*3+kt2][L],
                    W2[0][kt2], W2[1][kt2], W2[2][kt2], acc);
      }
      #pragma unroll
      for (int r=0;r<4;r++){
        int el = mt*16 + 4*q + r;
        float o = fmaxf(acc[r] + bb, 0.f);
        sn[el/20] += o;
      }
    }
    #pragma unroll
    for (int nd=0; nd<4; nd++){
      sn[nd] += __shfl_xor(sn[nd], 16);
      sn[nd] += __shfl_xor(sn[nd], 32);
    }
    if (L < 16){
      float* s2 = ws + O_S2;
      #pragma unroll
      for (int nd=0; nd<4; nd++)
        s2[(size_t)(n0+nd)*96 + 16*w + m] = sn[nd];
    }
  }
}

// ---------- per-step LSTM via split-3 bf16 MFMA, 16 nodes/block ----------
__global__ __launch_bounds__(384, 5) void k_lstm_mf(float* ws, const int* labels,
                                                    const float* msgb,
                                                    const float* outW, const float* outb,
                                                    float* out, int t)
{
  __shared__ bf16x8 aF[3][384];
  __shared__ bf16x8 hF[3][192];
  __shared__ float sh2[16*100];
  __shared__ float lgt[256];
  int tid = threadIdx.x;
  int w = tid >> 6, L = tid & 63;
  int m = L & 15, q = L >> 4;
  int b2 = blockIdx.x; b2 = (b2 & 7)*81 + (b2 >> 3);   // XCD swizzle, matches k_edge
  int nb = b2*16;
  const float hscale = (t == 0) ? 0.f : 1.f;

  // early independent prefetches: c (used after main GEMM) and gx (acc init)
  float cpre[4];
  {
    int jj = m + 16*w;
    #pragma unroll
    for (int r=0; r<4; r++)
      cpre[r] = ws[O_C + (size_t)(nb + q*4 + r)*96 + jj];
  }
  f32x4 acc[4];
  #pragma unroll
  for (int g=0; g<4; g++){
    int c384 = m + 16*(w + 6*g);
    acc[g] = *(const f32x4*)(ws + O_GX + (size_t)c384*NN + nb + 4*q);
  }

  {
    int ks = tid/64; int Ls = tid%64;
    int node = nb + (Ls & 15); int qs = Ls >> 4;
    const float* src = (ks < 3) ? (ws + O_S2 + (size_t)node*96 + 32*ks + 8*qs)
                                : (ws + O_H  + (size_t)node*96 + 32*(ks-3) + 8*qs);
    float sc = (ks < 3) ? 1.f : hscale;
    float4 v0 = *(const float4*)src;
    float4 v1 = *(const float4*)(src + 4);
    float r[8] = {v0.x,v0.y,v0.z,v0.w,v1.x,v1.y,v1.z,v1.w};
    bf16x8 vh, vm, vl;
    #pragma unroll
    for (int j=0;j<8;j++){
      short hh,mm,ll; split3(r[j]*sc, hh, mm, ll);
      vh[j]=hh; vm[j]=mm; vl[j]=ll;
    }
    aF[0][tid]=vh; aF[1][tid]=vm; aF[2][tid]=vl;
  }
  __syncthreads();

  const bf16x8* wl = (const bf16x8*)(ws + O_WL2);
  #pragma unroll 2
  for (int ks=0; ks<6; ks++){
    bf16x8 aH = aF[0][ks*64+L], aM = aF[1][ks*64+L], aLw = aF[2][ks*64+L];
    #pragma unroll
    for (int g=0; g<4; g++){
      int nt = w + 6*g;
      bf16x8 WH = wl[(size_t)(((0*24+nt)*6 + ks)*64) + L];
      bf16x8 WM = wl[(size_t)(((1*24+nt)*6 + ks)*64) + L];
      bf16x8 WL = wl[(size_t)(((2*24+nt)*6 + ks)*64) + L];
      acc[g] = mfma6(aH, aM, aLw, WH, WM, WL, acc[g]);
    }
  }

  {
    int jj = m + 16*w;
    #pragma unroll
    for (int r=0; r<4; r++){
      int n = nb + q*4 + r;
      float ig = sigm_fast(acc[0][r]);
      float fg = sigm_fast(acc[1][r]);
      float gg = tanh_fast(acc[2][r]);
      float og = sigm_fast(acc[3][r]);
      float nc = fg*cpre[r] + ig*gg;
      float nv = og*tanh_fast(nc);
      ws[O_C + (size_t)n*96 + jj] = nc;
      ws[O_H + (size_t)n*96 + jj] = nv;
      sh2[(q*4 + r)*100 + jj] = nv;
    }
  }
  __syncthreads();

  // hF staging on all 384 threads (2 threads per frag slot, b64 halves)
  {
    int s = tid >> 1;                    // frag slot 0..191
    int ks = s/64, Ls = s%64, qs = Ls >> 4;
    int half = tid & 1;
    const float* src = &sh2[(Ls & 15)*100 + 32*ks + 8*qs + 4*half];
    float4 v0 = *(const float4*)src;
    s16x4 vh, vm, vl;
    float rr[4] = {v0.x, v0.y, v0.z, v0.w};
    #pragma unroll
    for (int j=0;j<4;j++){
      short hh,mm,ll; split3(rr[j], hh, mm, ll);
      vh[j]=hh; vm[j]=mm; vl[j]=ll;
    }
    unsigned short* hp0 = (unsigned short*)&hF[0][s];
    unsigned short* hp1 = (unsigned short*)&hF[1][s];
    unsigned short* hp2 = (unsigned short*)&hF[2][s];
    *(s16x4*)(hp0 + 4*half) = vh;
    *(s16x4*)(hp1 + 4*half) = vm;
    *(s16x4*)(hp2 + 4*half) = vl;
  }
  __syncthreads();

  {
    const bf16x8* wab = (const bf16x8*)(ws + O_WAB2);
    f32x4 accA = {0.f,0.f,0.f,0.f};
    f32x4 accB = {0.f,0.f,0.f,0.f};
    #pragma unroll
    for (int ks=0; ks<3; ks++){
      bf16x8 hH = hF[0][ks*64+L], hM = hF[1][ks*64+L], hLw = hF[2][ks*64+L];
      accA = mfma6(hH, hM, hLw,
                   wab[(size_t)(((0*12+w)*3 + ks)*64) + L],
                   wab[(size_t)(((1*12+w)*3 + ks)*64) + L],
                   wab[(size_t)(((2*12+w)*3 + ks)*64) + L], accA);
      accB = mfma6(hH, hM, hLw,
                   wab[(size_t)(((0*12+w+6)*3 + ks)*64) + L],
                   wab[(size_t)(((1*12+w+6)*3 + ks)*64) + L],
                   wab[(size_t)(((2*12+w+6)*3 + ks)*64) + L], accB);
    }
    int jj = m + 16*w;
    float b0v = msgb[jj];
    #pragma unroll
    for (int r=0; r<4; r++){
      int n = nb + q*4 + r;
      ws[O_A  + (size_t)n*96 + jj] = accA[r];
      ws[O_BV + (size_t)n*96 + jj] = accB[r] + b0v;
    }
  }

  // logits via MFMA on wave 0: D col = class (lane&15), row = node (q*4+r)
  if (w == 0){
    const bf16x8* wo = (const bf16x8*)(ws + O_WO);
    float ob = (m < 10) ? outb[m] : 0.f;
    f32x4 lacc; lacc[0]=ob; lacc[1]=ob; lacc[2]=ob; lacc[3]=ob;
    #pragma unroll
    for (int ks=0; ks<3; ks++){
      lacc = mfma6(hF[0][ks*64+L], hF[1][ks*64+L], hF[2][ks*64+L],
                   wo[(size_t)((0*3 + ks)*64) + L],
                   wo[(size_t)((1*3 + ks)*64) + L],
                   wo[(size_t)((2*3 + ks)*64) + L], lacc);
    }
    #pragma unroll
    for (int r=0; r<4; r++){
      int n = nb + 4*q + r;
      lgt[(4*q + r)*16 + m] = lacc[r];
      if (m < 10)
        out[165889 + ((size_t)t*NN + n)*10 + m] = lacc[r];
    }
  }
  __syncthreads();
  if (tid < 16){
    int n = nb + tid;
    const float* Lg = &lgt[tid*16];
    float mx = Lg[0]; int bi = 0;
    #pragma unroll
    for (int cc=1;cc<10;cc++){ if (Lg[cc] > mx){ mx=Lg[cc]; bi=cc; } }
    float se = 0.f;
    #pragma unroll
    for (int cc=0;cc<10;cc++) se += expf(Lg[cc]-mx);
    int lab = labels[n];
    float lp = Lg[lab] - mx - logf(se);
    atomicAdd(ws + O_LOSS, -lp);
    out[t*NN + n] = (float)bi;
  }
}

// ---------- fallback per-step LSTM (VALU, no gx needed) ----------
__global__ __launch_bounds__(384) void k_lstm_valu(float* ws, const int* labels,
                                                   const float* msgb,
                                                   const float* outW, const float* outb,
                                                   float* out, int t)
{
  __shared__ float ss[768], sh[768], sx[768];
  __shared__ float lg[8*384];
  __shared__ float lh[8*97];
  __shared__ float lgt[80];
  int tid = threadIdx.x;
  int nb = blockIdx.x*8;
  const float* WC = ws + O_WCOMBT;
  const float* WH = ws + O_WHHT;
  float* h = ws + O_H; float* c = ws + O_C;
  const float hscale = (t == 0) ? 0.f : 1.f;

  for (int idx = tid; idx < 768; idx += 384){
    ss[idx] = ws[O_S2 + (size_t)nb*96 + idx];
    sh[idx] = ws[O_H  + (size_t)nb*96 + idx] * hscale;
    sx[idx] = ws[O_X + (size_t)nb*96 + idx];
  }
  float acc[8];
  float gb = ws[O_GB + tid];
  #pragma unroll
  for (int i=0;i<8;i++) acc[i] = gb;
  __syncthreads();

  {
    const float* WX = ws + O_WIHXT;
    #pragma unroll 2
    for (int k0=0;k0<96;k0+=4){
      float4 xv[8];
      #pragma unroll
      for (int i=0;i<8;i++) xv[i] = *(const float4*)&sx[i*96+k0];
      #pragma unroll
      for (int kk=0;kk<4;kk++){
        float w = WX[(k0+kk)*384 + tid];
        #pragma unroll
        for (int i=0;i<8;i++){
          float xe = (kk==0)?xv[i].x:(kk==1)?xv[i].y:(kk==2)?xv[i].z:xv[i].w;
          acc[i] = fmaf(w, xe, acc[i]);
        }
      }
    }
  }

  #pragma unroll 2
  for (int k0=0;k0<96;k0+=4){
    float4 sv[8], rv[8];
    #pragma unroll
    for (int i=0;i<8;i++){
      sv[i] = *(const float4*)&ss[i*96+k0];
      rv[i] = *(const float4*)&sh[i*96+k0];
    }
    #pragma unroll
    for (int kk=0;kk<4;kk++){
      float cw = WC[(k0+kk)*384 + tid];
      float hw = WH[(k0+kk)*384 + tid];
      #pragma unroll
      for (int i=0;i<8;i++){
        float se = (kk==0)?sv[i].x:(kk==1)?sv[i].y:(kk==2)?sv[i].z:sv[i].w;
        float re = (kk==0)?rv[i].x:(kk==1)?rv[i].y:(kk==2)?rv[i].z:rv[i].w;
        acc[i] = fmaf(cw, se, fmaf(hw, re, acc[i]));
      }
    }
  }
  #pragma unroll
  for (int i=0;i<8;i++) lg[i*384 + tid] = acc[i];
  __syncthreads();

  #pragma unroll
  for (int half=0; half<2; half++){
    int p = tid + half*384;
    int i = p/96, jj = p%96;
    int n = nb + i;
    float ig = sigm(lg[i*384 + jj]);
    float fg = sigm(lg[i*384 + 96 + jj]);
    float gg = tanhf(lg[i*384 + 192 + jj]);
    float og = sigm(lg[i*384 + 288 + jj]);
    float cv = c[(size_t)n*96 + jj];
    float nc = fg*cv + ig*gg;
    float nv = og*tanhf(nc);
    c[(size_t)n*96 + jj] = nc;
    h[(size_t)n*96 + jj] = nv;
    lh[i*97 + jj] = nv;
  }
  __syncthreads();

  {
    const float* WA = ws + O_W0AT; const float* WB = ws + O_W0BT;
    int q3 = tid/96, jj = tid%96;
    int i0 = q3*2;
    float aa0=0.f, aa1=0.f, ab0=0.f, ab1=0.f;
    #pragma unroll 2
    for (int k=0;k<96;k++){
      float wa = WA[k*96+jj], wb = WB[k*96+jj];
      float h0v = lh[i0*97 + k], h1v = lh[(i0+1)*97 + k];
      aa0 = fmaf(wa, h0v, aa0); ab0 = fmaf(wb, h0v, ab0);
      aa1 = fmaf(wa, h1v, aa1); ab1 = fmaf(wb, h1v, ab1);
    }
    float b0v = msgb[jj];
    float* Aa = ws + O_A; float* Bb = ws + O_BV;
    Aa[(size_t)(nb+i0)*96 + jj]   = aa0; Bb[(size_t)(nb+i0)*96 + jj]   = ab0 + b0v;
    Aa[(size_t)(nb+i0+1)*96 + jj] = aa1; Bb[(size_t)(nb+i0+1)*96 + jj] = ab1 + b0v;
  }

  if (tid < 80){
    int ln = tid/10, cls = tid%10;
    int n = nb + ln;
    float q0=outb[cls], q1=0.f, q2=0.f, q3v=0.f;
    const float* hr = &lh[ln*97];
    #pragma unroll
    for (int k=0;k<96;k+=4){
      q0=fmaf(outW[cls*96+k  ],hr[k  ],q0);  q1=fmaf(outW[cls*96+k+1],hr[k+1],q1);
      q2=fmaf(outW[cls*96+k+2],hr[k+2],q2);  q3v=fmaf(outW[cls*96+k+3],hr[k+3],q3v);
    }
    float lgv = (q0+q1)+(q2+q3v);
    lgt[ln*10 + cls] = lgv;
    out[165889 + ((size_t)t*NN + n)*10 + cls] = lgv;
  }
  __syncthreads();
  if (tid < 8){
    int n = nb + tid;
    const float* Lg = &lgt[tid*10];
    float mx = Lg[0]; int bi = 0;
    #pragma unroll
    for (int cc=1;cc<10;cc++){ if (Lg[cc] > mx){ mx=Lg[cc]; bi=cc; } }
    float se = 0.f;
    #pragma unroll
    for (int cc=0;cc<10;cc++) se += expf(Lg[cc]-mx);
    int lab = labels[n];
    float lp = Lg[lab] - mx - logf(se);
    atomicAdd(ws + O_LOSS, -lp);
    out[t*NN + n] = (float)bi;
  }
}

__global__ void k_final(float* ws, float* out){
  if (threadIdx.x == 0 && blockIdx.x == 0)
    out[165888] = ws[O_LOSS] / (float)(TT*NN);
}

extern "C" void kernel_launch(void* const* d_in, const int* in_sizes, int n_in,
                              void* d_out, int out_size, void* d_ws, size_t ws_size,
                              hipStream_t stream)
{
  (void)in_sizes; (void)n_in; (void)out_size;
  const int* q      = (const int*)d_in[0];
  const int* row    = (const int*)d_in[1];
  const int* col    = (const int*)d_in[2];
  const int* labels = (const int*)d_in[3];
  const int* dst    = (const int*)d_in[5];
  const float* demb  = (const float*)d_in[6];
  const float* remb  = (const float*)d_in[7];
  const float* cemb  = (const float*)d_in[8];
  const float* inW0  = (const float*)d_in[9];
  const float* inW   = (const float*)d_in[10];
  const float* inb   = (const float*)d_in[11];
  const float* msgW0 = (const float*)d_in[12];
  const float* msgW  = (const float*)d_in[13];
  const float* msgb  = (const float*)d_in[14];
  const float* Wih   = (const float*)d_in[15];
  const float* Whh   = (const float*)d_in[16];
  const float* outW  = (const float*)d_in[17];
  const float* outb  = (const float*)d_in[18];

  float* ws  = (float*)d_ws;
  float* out = (float*)d_out;

  const size_t need_gx = ((size_t)O_GX + (size_t)NN*384) * sizeof(float);
  const int use_mf = (ws_size >= need_gx) ? 1 : 0;

  hipLaunchKernelGGL(k_convert, dim3(487), dim3(256), 0, stream,
                     ws, msgW0, Whh, Wih, inW0, inW);
  hipLaunchKernelGGL(k_wfrag, dim3(27), dim3(256), 0, stream, ws, msgW);
  hipLaunchKernelGGL(k_wcomb, dim3(144), dim3(256), 0, stream, ws, Wih, msgW, msgb);
  if (use_mf){
    hipLaunchKernelGGL(k_wfin, dim3(36), dim3(256), 0, stream, ws, outW);
    hipLaunchKernelGGL(k_wl,  dim3(36), dim3(256), 0, stream, ws);
    hipLaunchKernelGGL(k_wab, dim3(9),  dim3(256), 0, stream, ws);
    hipLaunchKernelGGL(k_input_mf, dim3(648), dim3(384), 0, stream,
                       ws, q, row, col, demb, remb, cemb, inb, msgb);
  } else {
    hipLaunchKernelGGL(k_input, dim3(648), dim3(192), 0, stream,
                       ws, q, row, col, demb, remb, cemb, inb, msgb);
  }
  for (int t=0; t<TT; ++t){
    hipLaunchKernelGGL(k_edge, dim3(EE/80), dim3(384), 0, stream, ws, dst, msgb);
    if (use_mf)
      hipLaunchKernelGGL(k_lstm_mf, dim3(NN/16), dim3(384), 0, stream,
                         ws, labels, msgb, outW, outb, out, t);
    else
      hipLaunchKernelGGL(k_lstm_valu, dim3(1296), dim3(384), 0, stream,
                         ws, labels, msgb, outW, outb, out, t);
  }
  hipLaunchKernelGGL(k_final, dim3(1), dim3(64), 0, stream, ws, out);
}